// Round 1
// baseline (590.857 us; speedup 1.0000x reference)
//
#include <hip/hip_runtime.h>

// 100 / ln(2): reference divides by T=0.01 then uses e-base LSE; we work in
// base-2 throughout (v_exp_f32 computes 2^x natively).
#define SCALE 144.269504088896340736f

// DPP move helper (compile-time ctrl). bound_ctrl=true, all rows/banks.
template <int CTRL>
__device__ __forceinline__ float dppf(float x) {
    return __builtin_bit_cast(
        float, __builtin_amdgcn_update_dpp(0, __builtin_bit_cast(int, x),
                                           CTRL, 0xF, 0xF, true));
}

// Reduce over the 4 "b" lanes (quad): quad_perm ror1 (0x39), ror2 (0x4E).
__device__ __forceinline__ float qsum(float x) {
    x += dppf<0x39>(x);
    x += dppf<0x4E>(x);
    return x;  // all 4 lanes hold the total
}
__device__ __forceinline__ float qmax(float x) {
    x = fmaxf(x, dppf<0x39>(x));
    x = fmaxf(x, dppf<0x4E>(x));
    return x;
}
// Reduce over the 4 "a" lanes (stride 4 inside a 16-lane DPP row):
// row_ror:4 (0x124), row_ror:8 (0x128). (l+4k) mod 16 preserves b = l%4.
__device__ __forceinline__ float asum(float x) {
    x += dppf<0x124>(x);
    x += dppf<0x128>(x);
    return x;
}
__device__ __forceinline__ float amax(float x) {
    x = fmaxf(x, dppf<0x124>(x));
    x = fmaxf(x, dppf<0x128>(x));
    return x;
}

// One matrix per 16-lane DPP row; 4 matrices per wave; 16 per 256-thread block.
// Lane (q,a,b): holds C[a*9+r][b*9+s], r,s in [0,9): 81 VGPRs.
__global__ __launch_bounds__(256, 4) void sinkhorn_kernel(
    const float* __restrict__ in, float* __restrict__ out) {
    const int lane = threadIdx.x & 63;
    const int wv   = threadIdx.x >> 6;
    const int q    = lane >> 4;         // matrix within wave
    const int a    = (lane >> 2) & 3;   // row-block
    const int b    = lane & 3;          // col-block
    const int m    = blockIdx.x * 16 + wv * 4 + q;

    const float* src = in  + (size_t)m * 1296 + (a * 9) * 36 + b * 9;
    float*       dst = out + (size_t)m * 1296 + (a * 9) * 36 + b * 9;

    float C[81];
    #pragma unroll
    for (int r = 0; r < 9; ++r)
        #pragma unroll
        for (int s = 0; s < 9; ++s)
            C[r * 9 + s] = src[r * 36 + s] * SCALE;  // L in log2 domain

    // a2[r] = row max (local max over s, then over b-lanes)
    float a2[9], u[9], w[9];
    #pragma unroll
    for (int r = 0; r < 9; ++r) {
        float mx = C[r * 9];
        #pragma unroll
        for (int s = 1; s < 9; ++s) mx = fmaxf(mx, C[r * 9 + s]);
        a2[r] = qmax(mx);
    }

    // u^(1)_i = 1 / sum_j 2^(L - a)   (first row step; avoids degenerate w0)
    #pragma unroll
    for (int r = 0; r < 9; ++r) {
        float acc = 0.f;
        #pragma unroll
        for (int s = 0; s < 9; ++s)
            acc += __builtin_amdgcn_exp2f(C[r * 9 + s] - a2[r]);
        u[r] = __builtin_amdgcn_rcpf(qsum(acc));
    }

    // b2[s] = col max of (L - a2)  (local over r, then over a-lanes)
    float b2[9];
    #pragma unroll
    for (int s = 0; s < 9; ++s) {
        float mx = C[s] - a2[0];
        #pragma unroll
        for (int r = 1; r < 9; ++r) mx = fmaxf(mx, C[r * 9 + s] - a2[r]);
        b2[s] = amax(mx);
    }

    // C = 2^(L - a2 - b2): every row AND every column contains a 1.0.
    #pragma unroll
    for (int r = 0; r < 9; ++r)
        #pragma unroll
        for (int s = 0; s < 9; ++s)
            C[r * 9 + s] = __builtin_amdgcn_exp2f(C[r * 9 + s] - a2[r] - b2[s]);

    // w^(1)_j = 1 / sum_i C_ij u_i   (first col step)
    #pragma unroll
    for (int s = 0; s < 9; ++s) {
        float acc = 0.f;
        #pragma unroll
        for (int r = 0; r < 9; ++r) acc = fmaf(C[r * 9 + s], u[r], acc);
        w[s] = __builtin_amdgcn_rcpf(asum(acc));
    }

    // 20 more full iterations (21 row steps + 21 col steps total)
    #pragma unroll 1
    for (int it = 0; it < 20; ++it) {
        #pragma unroll
        for (int r = 0; r < 9; ++r) {
            float acc = 0.f;
            #pragma unroll
            for (int s = 0; s < 9; ++s) acc = fmaf(C[r * 9 + s], w[s], acc);
            u[r] = __builtin_amdgcn_rcpf(qsum(acc));
        }
        #pragma unroll
        for (int s = 0; s < 9; ++s) {
            float acc = 0.f;
            #pragma unroll
            for (int r = 0; r < 9; ++r) acc = fmaf(C[r * 9 + s], u[r], acc);
            w[s] = __builtin_amdgcn_rcpf(asum(acc));
        }
    }

    // P = C * u_i * w_j
    #pragma unroll
    for (int r = 0; r < 9; ++r) {
        const float ur = u[r];
        #pragma unroll
        for (int s = 0; s < 9; ++s)
            dst[r * 36 + s] = C[r * 9 + s] * ur * w[s];
    }
}

extern "C" void kernel_launch(void* const* d_in, const int* in_sizes, int n_in,
                              void* d_out, int out_size, void* d_ws, size_t ws_size,
                              hipStream_t stream) {
    const float* in  = (const float*)d_in[0];
    float*       out = (float*)d_out;
    // 65536 matrices, 16 per block -> 4096 blocks of 256 threads.
    sinkhorn_kernel<<<dim3(4096), dim3(256), 0, stream>>>(in, out);
}